// Round 4
// baseline (326.106 us; speedup 1.0000x reference)
//
#include <hip/hip_runtime.h>
#include <hip/hip_bf16.h>

// HeteroAttLayer: h = tanh(hs @ W^T + b); att = softmax(mean_n h.meta); out = sum_c att[c]*h[c]
// C=4, N=300000, D=128.
// R4: materialize h (bf16) in ws. Pass1: read hs once (NT), GEMM+tanh, write h + score partials.
//     Pass3: pure elementwise weighted channel-sum reading h (mostly L3-hit), NT out stores.
//     MFMA operand-swap makes each lane hold 4 consecutive e -> coalesced 8B h stores, no LDS transpose.

#define C_CH 4
#define N_NODES 300000
#define D_DIM 128
#define M_TILE 96
#define N_TILES (N_NODES / M_TILE)   // 3125 exactly, no tail
#define H_TILE_ELEMS (C_CH * M_TILE * D_DIM)   // 49152 bf16 per tile (all channels)

typedef short bf16x8 __attribute__((ext_vector_type(8)));   // 8 bf16 (4 VGPRs)
typedef float floatx4 __attribute__((ext_vector_type(4)));
typedef unsigned int uintx2 __attribute__((ext_vector_type(2)));
typedef unsigned int uintx4 __attribute__((ext_vector_type(4)));
typedef unsigned short ushortx8 __attribute__((ext_vector_type(8)));

__device__ __forceinline__ unsigned pack_bf16_rne(float a, float b) {
    unsigned ua = __builtin_bit_cast(unsigned, a);
    unsigned ub = __builtin_bit_cast(unsigned, b);
    ua += 0x7FFFu + ((ua >> 16) & 1u);   // round-to-nearest-even
    ub += 0x7FFFu + ((ub >> 16) & 1u);
    return (ua >> 16) | (ub & 0xFFFF0000u);
}

// tanh via v_exp_f32: tanh|x| = 1 - 2/(exp(2|x|)+1); error ~1e-6 << 2e-2 threshold
__device__ __forceinline__ float fast_tanh(float x) {
    float ax = __builtin_fabsf(x);
    float e = __builtin_amdgcn_exp2f(ax * 2.8853900817779268f);  // 2*log2(e)
    float t = 1.0f - 2.0f * __builtin_amdgcn_rcpf(e + 1.0f);
    return __builtin_copysignf(t, x);
}

// Swizzled LDS byte offset for bf16 (row, d); row stride 256 B. XOR (row&7)<<4
// breaks the stride-256B column bank conflict (guide §6 G4), keeps 16B alignment.
__device__ __forceinline__ int lds_off(int row, int d) {
    return row * 256 + ((d * 2) ^ ((row & 7) << 4));
}

// W fragments in registers: bfr[et][s] = bf16 of W[e][s*32+(lane>>4)*8 .. +7],
// e = wave*32 + et*16 + (lane&15).
__device__ __forceinline__ void load_w_frags(const float* __restrict__ W,
                                             int wave, int lane, bf16x8 (&bfr)[2][4]) {
    int l15 = lane & 15, q = lane >> 4;
    #pragma unroll
    for (int et = 0; et < 2; ++et)
        #pragma unroll
        for (int s = 0; s < 4; ++s) {
            int e = wave * 32 + et * 16 + l15;
            int d0 = s * 32 + q * 8;
            const floatx4* p = reinterpret_cast<const floatx4*>(W + e * D_DIM + d0);
            floatx4 v0 = p[0], v1 = p[1];
            uintx4 u;
            u.x = pack_bf16_rne(v0.x, v0.y);
            u.y = pack_bf16_rne(v0.z, v0.w);
            u.z = pack_bf16_rne(v1.x, v1.y);
            u.w = pack_bf16_rne(v1.z, v1.w);
            bfr[et][s] = __builtin_bit_cast(bf16x8, u);
        }
}

// Pass 1: per (c, tile): z = hs_tile @ W^T; h = tanh(z+b); write h (bf16) to ws;
// partial score = sum h . meta[c].
// MFMA operand-swap: acc = mfma(Wfrag, Afrag, acc) -> D[e][n] with col(lane&15)=n,
// row=(lane>>4)*4+r = e-within-32. Each lane holds 4 consecutive e at fixed n ->
// pack 4 bf16 = 8B coalescible store.
__global__ __launch_bounds__(256, 3) void score_kernel(
        const float* __restrict__ hs, const float* __restrict__ W,
        const float* __restrict__ bvec, const float* __restrict__ meta,
        unsigned short* __restrict__ hws, float* __restrict__ partials) {
    __shared__ short As[M_TILE * D_DIM];
    __shared__ float red[4];
    int c = blockIdx.x, tile = blockIdx.y, tid = threadIdx.x;
    int wave = tid >> 6, lane = tid & 63;
    int l15 = lane & 15, q = lane >> 4;

    bf16x8 bfr[2][4];
    load_w_frags(W, wave, lane, bfr);

    // stage hs tile -> bf16 swizzled LDS (NT loads: hs is read exactly once)
    const float* src = hs + (size_t)c * N_NODES * D_DIM + (size_t)tile * M_TILE * D_DIM;
    #pragma unroll
    for (int j = 0; j < 12; ++j) {              // 96*32/256 float4 per thread
        int qq = j * 256 + tid;
        floatx4 v = __builtin_nontemporal_load(reinterpret_cast<const floatx4*>(src) + qq);
        int row = qq >> 5, d0 = (qq & 31) * 4;
        uintx2 w;
        w.x = pack_bf16_rne(v.x, v.y);
        w.y = pack_bf16_rne(v.z, v.w);
        *reinterpret_cast<uintx2*>(reinterpret_cast<char*>(As) + lds_off(row, d0)) = w;
    }
    __syncthreads();

    floatx4 acc[6][2];
    #pragma unroll
    for (int mt = 0; mt < 6; ++mt)
        #pragma unroll
        for (int et = 0; et < 2; ++et)
            acc[mt][et] = (floatx4){0.f, 0.f, 0.f, 0.f};

    #pragma unroll
    for (int s = 0; s < 4; ++s) {
        int d0 = s * 32 + q * 8;
        bf16x8 a[6];
        #pragma unroll
        for (int mt = 0; mt < 6; ++mt)
            a[mt] = *reinterpret_cast<const bf16x8*>(
                        reinterpret_cast<const char*>(As) + lds_off(mt * 16 + l15, d0));
        #pragma unroll
        for (int mt = 0; mt < 6; ++mt)
            #pragma unroll
            for (int et = 0; et < 2; ++et)
                acc[mt][et] = __builtin_amdgcn_mfma_f32_16x16x32_bf16(bfr[et][s], a[mt], acc[mt][et], 0, 0, 0);
    }

    // epilogue: lane holds z[n][e0..e0+3], n = mt*16+l15, e0 = wave*32+et*16+q*4
    floatx4 bvv[2], mvv[2];
    #pragma unroll
    for (int et = 0; et < 2; ++et) {
        int e0 = wave * 32 + et * 16 + q * 4;
        bvv[et] = *reinterpret_cast<const floatx4*>(bvec + e0);
        mvv[et] = *reinterpret_cast<const floatx4*>(meta + c * D_DIM + e0);
    }
    unsigned short* htile = hws + (size_t)tile * H_TILE_ELEMS + c * (M_TILE * D_DIM);
    float p = 0.f;
    #pragma unroll
    for (int mt = 0; mt < 6; ++mt) {
        int n = mt * 16 + l15;
        #pragma unroll
        for (int et = 0; et < 2; ++et) {
            int e0 = wave * 32 + et * 16 + q * 4;
            float hv[4];
            #pragma unroll
            for (int r = 0; r < 4; ++r) {
                hv[r] = fast_tanh(acc[mt][et][r] + bvv[et][r]);
                p += hv[r] * mvv[et][r];
            }
            uintx2 u;
            u.x = pack_bf16_rne(hv[0], hv[1]);
            u.y = pack_bf16_rne(hv[2], hv[3]);
            *reinterpret_cast<uintx2*>(htile + n * D_DIM + e0) = u;   // regular store: keep in L3
        }
    }
    #pragma unroll
    for (int off = 32; off > 0; off >>= 1) p += __shfl_down(p, off);
    if (lane == 0) red[wave] = p;
    __syncthreads();
    if (tid == 0) partials[c * N_TILES + tile] = red[0] + red[1] + red[2] + red[3];
}

// Pass 2: deterministic reduce + softmax over 4 channels
__global__ void softmax_kernel(const float* __restrict__ partials, float* __restrict__ att_out) {
    __shared__ float red[4];
    __shared__ float totals[C_CH];
    int tid = threadIdx.x;
    int wave = tid >> 6, lane = tid & 63;
    for (int c = 0; c < C_CH; ++c) {
        float s = 0.f;
        for (int i = tid; i < N_TILES; i += 256) s += partials[c * N_TILES + i];
        #pragma unroll
        for (int off = 32; off > 0; off >>= 1) s += __shfl_down(s, off);
        if (lane == 0) red[wave] = s;
        __syncthreads();
        if (tid == 0) totals[c] = red[0] + red[1] + red[2] + red[3];
        __syncthreads();
    }
    if (tid == 0) {
        float sc[C_CH], m = -1e30f;
        #pragma unroll
        for (int c = 0; c < C_CH; ++c) {
            sc[c] = totals[c] / (float)N_NODES;
            m = fmaxf(m, sc[c]);
        }
        float sum = 0.f;
        #pragma unroll
        for (int c = 0; c < C_CH; ++c) {
            sc[c] = __builtin_amdgcn_exp2f((sc[c] - m) * 1.4426950408889634f);
            sum += sc[c];
        }
        #pragma unroll
        for (int c = 0; c < C_CH; ++c) att_out[c] = sc[c] / sum;
    }
}

// Pass 3: out[n][d] = sum_c att[c] * h[c][n][d]. Pure elementwise; reversed tile
// order so the L3-resident tail of h (written last by pass 1) is consumed first.
__global__ __launch_bounds__(256, 8) void combine_kernel(
        const unsigned short* __restrict__ hws, const float* __restrict__ att,
        float* __restrict__ out) {
    int tile = N_TILES - 1 - blockIdx.x;
    int tid = threadIdx.x;
    float av[C_CH];
    #pragma unroll
    for (int c = 0; c < C_CH; ++c) av[c] = att[c];

    const unsigned short* base = hws + (size_t)tile * H_TILE_ELEMS;
    float* obase = out + (size_t)tile * (M_TILE * D_DIM);

    #pragma unroll
    for (int j = 0; j < 6; ++j) {               // 12288 elems / (256 thr * 8)
        int idx = j * 2048 + tid * 8;
        float sum[8];
        #pragma unroll
        for (int i = 0; i < 8; ++i) sum[i] = 0.f;
        #pragma unroll
        for (int c = 0; c < C_CH; ++c) {
            ushortx8 hv = *reinterpret_cast<const ushortx8*>(base + c * (M_TILE * D_DIM) + idx);
            #pragma unroll
            for (int i = 0; i < 8; ++i) {
                float f = __builtin_bit_cast(float, (unsigned)hv[i] << 16);
                sum[i] += av[c] * f;
            }
        }
        floatx4 o0 = {sum[0], sum[1], sum[2], sum[3]};
        floatx4 o1 = {sum[4], sum[5], sum[6], sum[7]};
        __builtin_nontemporal_store(o0, reinterpret_cast<floatx4*>(obase + idx));
        __builtin_nontemporal_store(o1, reinterpret_cast<floatx4*>(obase + idx + 4));
    }
}

extern "C" void kernel_launch(void* const* d_in, const int* in_sizes, int n_in,
                              void* d_out, int out_size, void* d_ws, size_t ws_size,
                              hipStream_t stream) {
    (void)in_sizes; (void)n_in; (void)out_size; (void)ws_size;
    const float* hs   = (const float*)d_in[0];
    const float* W    = (const float*)d_in[1];
    const float* bv   = (const float*)d_in[2];
    const float* meta = (const float*)d_in[3];
    unsigned short* hws = (unsigned short*)d_ws;              // [3125][4][96][128] bf16 = 307.2 MB
    float* partials = (float*)d_ws + 76800000;                // [4][3125]
    float* att      = partials + C_CH * N_TILES;              // [4]
    float* out      = (float*)d_out;

    // grid x = channel (fast), y = tile -> dispatch is tile-major ascending:
    // the last-written h tiles (all 4 channels) are L3-resident for pass 3's reversed walk.
    score_kernel<<<dim3(C_CH, N_TILES), 256, 0, stream>>>(hs, W, bv, meta, hws, partials);
    softmax_kernel<<<1, 256, 0, stream>>>(partials, att);
    combine_kernel<<<N_TILES, 256, 0, stream>>>(hws, att, out);
}

// Round 5
// 235.995 us; speedup vs baseline: 1.3818x; 1.3818x over previous
//
#include <hip/hip_runtime.h>
#include <hip/hip_bf16.h>

// HeteroAttLayer: h = tanh(hs @ W^T + b); att = softmax(mean_n h.meta); out = sum_c att[c]*h[c]
// C=4, N=300000, D=128.
// R5: materialize h as INT8 in ws (153.6 MB -> L3-resident). Pass1 reads hs once (NT),
//     GEMM+tanh, quantizes h, stores coalesced via LDS-transpose; pass3 is an elementwise
//     int8 weighted channel-sum whose reads are mostly L3 hits. Convex combination keeps
//     quant error <= 0.0039.

#define C_CH 4
#define N_NODES 300000
#define D_DIM 128
#define M_TILE 96
#define N_TILES (N_NODES / M_TILE)          // 3125 exactly, no tail
#define TILE_BYTES (M_TILE * D_DIM)         // 12288 int8 per (tile, channel)
#define H_TILE_BYTES (C_CH * TILE_BYTES)    // 49152 int8 per tile (all channels)

typedef short bf16x8 __attribute__((ext_vector_type(8)));   // 8 bf16 (4 VGPRs)
typedef float floatx4 __attribute__((ext_vector_type(4)));
typedef unsigned int uintx2 __attribute__((ext_vector_type(2)));
typedef unsigned int uintx4 __attribute__((ext_vector_type(4)));

__device__ __forceinline__ unsigned pack_bf16_rne(float a, float b) {
    unsigned ua = __builtin_bit_cast(unsigned, a);
    unsigned ub = __builtin_bit_cast(unsigned, b);
    ua += 0x7FFFu + ((ua >> 16) & 1u);   // round-to-nearest-even
    ub += 0x7FFFu + ((ub >> 16) & 1u);
    return (ua >> 16) | (ub & 0xFFFF0000u);
}

// tanh via v_exp_f32: tanh|x| = 1 - 2/(exp(2|x|)+1); error ~1e-6 << 2e-2 threshold
__device__ __forceinline__ float fast_tanh(float x) {
    float ax = __builtin_fabsf(x);
    float e = __builtin_amdgcn_exp2f(ax * 2.8853900817779268f);  // 2*log2(e)
    float t = 1.0f - 2.0f * __builtin_amdgcn_rcpf(e + 1.0f);
    return __builtin_copysignf(t, x);
}

// Swizzled LDS byte offset for bf16 (row, d); row stride 256 B. XOR (row&7)<<4
// breaks the stride-256B column bank conflict (guide §6 G4), keeps 16B alignment.
__device__ __forceinline__ int lds_off(int row, int d) {
    return row * 256 + ((d * 2) ^ ((row & 7) << 4));
}

// Swizzled byte offset into the int8 transpose buffer [96][128]: row stride 128 B
// (= exactly 32 banks), XOR (n&7)<<4 spreads same-column lanes over 8 banks ->
// 2 lanes/bank on ds_write_b32 (free, m136); preserves 16B granules for b128 reads.
__device__ __forceinline__ int t_off(int n, int e) {
    return n * 128 + (e ^ ((n & 7) << 4));
}

// W fragments in registers: bfr[et][s] = bf16 of W[e][s*32+(lane>>4)*8 .. +7],
// e = wave*32 + et*16 + (lane&15).
__device__ __forceinline__ void load_w_frags(const float* __restrict__ W,
                                             int wave, int lane, bf16x8 (&bfr)[2][4]) {
    int l15 = lane & 15, q = lane >> 4;
    #pragma unroll
    for (int et = 0; et < 2; ++et)
        #pragma unroll
        for (int s = 0; s < 4; ++s) {
            int e = wave * 32 + et * 16 + l15;
            int d0 = s * 32 + q * 8;
            const floatx4* p = reinterpret_cast<const floatx4*>(W + e * D_DIM + d0);
            floatx4 v0 = p[0], v1 = p[1];
            uintx4 u;
            u.x = pack_bf16_rne(v0.x, v0.y);
            u.y = pack_bf16_rne(v0.z, v0.w);
            u.z = pack_bf16_rne(v1.x, v1.y);
            u.w = pack_bf16_rne(v1.z, v1.w);
            bfr[et][s] = __builtin_bit_cast(bf16x8, u);
        }
}

// Pass 1: per (c, tile): z = hs_tile @ W^T (swapped operands -> lane holds 4 consecutive e);
// h = tanh(z+b); partial score = sum h.meta[c]; h -> int8, LDS-transpose, coalesced store.
__global__ __launch_bounds__(256, 4) void score_kernel(
        const float* __restrict__ hs, const float* __restrict__ W,
        const float* __restrict__ bvec, const float* __restrict__ meta,
        unsigned char* __restrict__ h8, float* __restrict__ partials) {
    __shared__ short As[M_TILE * D_DIM];     // 24 KB; reused as int8 transpose buffer
    __shared__ float red[4];
    int c = blockIdx.x, tile = blockIdx.y, tid = threadIdx.x;
    int wave = tid >> 6, lane = tid & 63;
    int l15 = lane & 15, q = lane >> 4;

    bf16x8 bfr[2][4];
    load_w_frags(W, wave, lane, bfr);

    // stage hs tile -> bf16 swizzled LDS. NT loads: hs is read exactly once; keep it
    // out of L3 so the resident h8 working set survives.
    const float* src = hs + (size_t)c * N_NODES * D_DIM + (size_t)tile * M_TILE * D_DIM;
    #pragma unroll
    for (int j = 0; j < 12; ++j) {              // 96*32/256 float4 per thread
        int qq = j * 256 + tid;
        floatx4 v = __builtin_nontemporal_load(reinterpret_cast<const floatx4*>(src) + qq);
        int row = qq >> 5, d0 = (qq & 31) * 4;
        uintx2 w;
        w.x = pack_bf16_rne(v.x, v.y);
        w.y = pack_bf16_rne(v.z, v.w);
        *reinterpret_cast<uintx2*>(reinterpret_cast<char*>(As) + lds_off(row, d0)) = w;
    }
    __syncthreads();

    floatx4 acc[6][2];
    #pragma unroll
    for (int mt = 0; mt < 6; ++mt)
        #pragma unroll
        for (int et = 0; et < 2; ++et)
            acc[mt][et] = (floatx4){0.f, 0.f, 0.f, 0.f};

    #pragma unroll
    for (int s = 0; s < 4; ++s) {
        int d0 = s * 32 + q * 8;
        bf16x8 a[6];
        #pragma unroll
        for (int mt = 0; mt < 6; ++mt)
            a[mt] = *reinterpret_cast<const bf16x8*>(
                        reinterpret_cast<const char*>(As) + lds_off(mt * 16 + l15, d0));
        #pragma unroll
        for (int mt = 0; mt < 6; ++mt)
            #pragma unroll
            for (int et = 0; et < 2; ++et)
                acc[mt][et] = __builtin_amdgcn_mfma_f32_16x16x32_bf16(bfr[et][s], a[mt], acc[mt][et], 0, 0, 0);
    }

    // epilogue: lane holds z[n][e0..e0+3], n = mt*16+l15, e0 = wave*32+et*16+q*4
    // (verified layout: R4 passed with this mapping)
    floatx4 bvv[2], mvv[2];
    #pragma unroll
    for (int et = 0; et < 2; ++et) {
        int e0 = wave * 32 + et * 16 + q * 4;
        bvv[et] = *reinterpret_cast<const floatx4*>(bvec + e0);
        mvv[et] = *reinterpret_cast<const floatx4*>(meta + c * D_DIM + e0);
    }
    unsigned pk[6][2];
    float p = 0.f;
    #pragma unroll
    for (int mt = 0; mt < 6; ++mt)
        #pragma unroll
        for (int et = 0; et < 2; ++et) {
            unsigned u = 0;
            #pragma unroll
            for (int r = 0; r < 4; ++r) {
                float hv = fast_tanh(acc[mt][et][r] + bvv[et][r]);
                p += hv * mvv[et][r];
                int iq = (int)__builtin_rintf(hv * 127.0f);
                u |= ((unsigned)iq & 0xFFu) << (8 * r);
            }
            pk[mt][et] = u;
        }

    __syncthreads();   // all waves done reading As -> safe to reuse as transpose buffer
    char* tb = reinterpret_cast<char*>(As);
    #pragma unroll
    for (int mt = 0; mt < 6; ++mt)
        #pragma unroll
        for (int et = 0; et < 2; ++et) {
            int n = mt * 16 + l15;
            int e0 = wave * 32 + et * 16 + q * 4;
            *reinterpret_cast<unsigned*>(tb + t_off(n, e0)) = pk[mt][et];
        }
    __syncthreads();

    // coalesced writeback: thread owns 48 contiguous bytes of [96][128] int8
    unsigned char* dst = h8 + (size_t)tile * H_TILE_BYTES + c * TILE_BYTES + tid * 48;
    #pragma unroll
    for (int i = 0; i < 3; ++i) {
        int g = tid * 48 + i * 16;
        int n = g >> 7, e = g & 127;
        uintx4 v = *reinterpret_cast<const uintx4*>(tb + t_off(n, e));
        *reinterpret_cast<uintx4*>(dst + i * 16) = v;
    }

    #pragma unroll
    for (int off = 32; off > 0; off >>= 1) p += __shfl_down(p, off);
    if (lane == 0) red[wave] = p;
    __syncthreads();
    if (tid == 0) partials[c * N_TILES + tile] = red[0] + red[1] + red[2] + red[3];
}

// Pass 2: deterministic reduce + softmax over 4 channels (1024 threads)
__global__ void softmax_kernel(const float* __restrict__ partials, float* __restrict__ att_out) {
    __shared__ float red[16];
    __shared__ float totals[C_CH];
    int tid = threadIdx.x;
    int wave = tid >> 6, lane = tid & 63;
    for (int c = 0; c < C_CH; ++c) {
        float s = 0.f;
        for (int i = tid; i < N_TILES; i += 1024) s += partials[c * N_TILES + i];
        #pragma unroll
        for (int off = 32; off > 0; off >>= 1) s += __shfl_down(s, off);
        if (lane == 0) red[wave] = s;
        __syncthreads();
        if (tid == 0) {
            float t = 0.f;
            #pragma unroll
            for (int w = 0; w < 16; ++w) t += red[w];
            totals[c] = t;
        }
        __syncthreads();
    }
    if (tid == 0) {
        float sc[C_CH], m = -1e30f;
        #pragma unroll
        for (int c = 0; c < C_CH; ++c) {
            sc[c] = totals[c] / (float)N_NODES;
            m = fmaxf(m, sc[c]);
        }
        float sum = 0.f;
        #pragma unroll
        for (int c = 0; c < C_CH; ++c) {
            sc[c] = __builtin_amdgcn_exp2f((sc[c] - m) * 1.4426950408889634f);
            sum += sc[c];
        }
        #pragma unroll
        for (int c = 0; c < C_CH; ++c) att_out[c] = sc[c] / sum;
    }
}

// Pass 3: out[n][e] = sum_c att[c]/127 * h8[c][n][e]. Reversed tile order consumes the
// most-recently-written (least-evicted) h8 first; normal loads (want L3 hits), NT out stores.
__global__ __launch_bounds__(256, 8) void combine_kernel(
        const unsigned char* __restrict__ h8, const float* __restrict__ att,
        float* __restrict__ out) {
    int tile = N_TILES - 1 - blockIdx.x;
    int tid = threadIdx.x;
    float av[C_CH];
    #pragma unroll
    for (int c = 0; c < C_CH; ++c) av[c] = att[c] * (1.0f / 127.0f);  // fold dequant scale

    const unsigned char* base = h8 + (size_t)tile * H_TILE_BYTES;
    float* obase = out + (size_t)tile * (M_TILE * D_DIM);

    #pragma unroll
    for (int j = 0; j < 6; ++j) {               // 12288 elems / (256 thr * 8)
        int idx = j * 2048 + tid * 8;
        float sum[8];
        #pragma unroll
        for (int i = 0; i < 8; ++i) sum[i] = 0.f;
        #pragma unroll
        for (int c = 0; c < C_CH; ++c) {
            uintx2 u = *reinterpret_cast<const uintx2*>(base + c * TILE_BYTES + idx);
            #pragma unroll
            for (int i = 0; i < 4; ++i) {
                int b0 = (int)(u.x << (24 - 8 * i)) >> 24;   // sign-extend byte i
                int b1 = (int)(u.y << (24 - 8 * i)) >> 24;
                sum[i]     += av[c] * (float)b0;
                sum[i + 4] += av[c] * (float)b1;
            }
        }
        floatx4 o0 = {sum[0], sum[1], sum[2], sum[3]};
        floatx4 o1 = {sum[4], sum[5], sum[6], sum[7]};
        __builtin_nontemporal_store(o0, reinterpret_cast<floatx4*>(obase + idx));
        __builtin_nontemporal_store(o1, reinterpret_cast<floatx4*>(obase + idx + 4));
    }
}

extern "C" void kernel_launch(void* const* d_in, const int* in_sizes, int n_in,
                              void* d_out, int out_size, void* d_ws, size_t ws_size,
                              hipStream_t stream) {
    (void)in_sizes; (void)n_in; (void)out_size; (void)ws_size;
    const float* hs   = (const float*)d_in[0];
    const float* W    = (const float*)d_in[1];
    const float* bv   = (const float*)d_in[2];
    const float* meta = (const float*)d_in[3];
    unsigned char* h8 = (unsigned char*)d_ws;                       // [3125][4][96][128] int8 = 153.6 MB
    float* partials = (float*)((char*)d_ws + 153600000);            // [4][3125]
    float* att      = partials + C_CH * N_TILES;                    // [4]
    float* out      = (float*)d_out;

    // grid x = channel (fast), y = tile -> tile-major dispatch: last-written h8 tiles
    // (all 4 channels together) are the L3-resident tail for pass 3's reversed walk.
    score_kernel<<<dim3(C_CH, N_TILES), 256, 0, stream>>>(hs, W, bv, meta, h8, partials);
    softmax_kernel<<<1, 1024, 0, stream>>>(partials, att);
    combine_kernel<<<N_TILES, 256, 0, stream>>>(h8, att, out);
}